// Round 5
// baseline (525.586 us; speedup 1.0000x reference)
//
#include <hip/hip_runtime.h>

typedef __bf16 bf16;
typedef _Float16 f16;
typedef f16  f16x8  __attribute__((ext_vector_type(8)));
typedef f16  f16x4v __attribute__((ext_vector_type(4)));
typedef float f32x4 __attribute__((ext_vector_type(4)));

#define MFMA_F16(a,b,c) __builtin_amdgcn_mfma_f32_16x16x32_f16((a),(b),(c),0,0,0)

#define NWIN 512
#define NTOK 64
#define NH 8
#define HD 32
#define DIM 256

// load 8 consecutive fp32, round to f16x8
__device__ __forceinline__ f16x8 ld_f16x8(const float* __restrict__ p) {
  f32x4 a = *(const f32x4*)p;
  f32x4 b = *(const f32x4*)(p + 4);
  f16x8 r;
  r[0] = (f16)a[0]; r[1] = (f16)a[1]; r[2] = (f16)a[2]; r[3] = (f16)a[3];
  r[4] = (f16)b[0]; r[5] = (f16)b[1]; r[6] = (f16)b[2]; r[7] = (f16)b[3];
  return r;
}

// ---------------- prep: CPB MLP -> 16*sigmoid(bias) table [2][225][8] f32 ----
__global__ void prep_cpb(const float* __restrict__ w1a, const float* __restrict__ b1a,
                         const float* __restrict__ w2a,
                         const float* __restrict__ w1b, const float* __restrict__ b1b,
                         const float* __restrict__ w2b,
                         float* __restrict__ sg16) {
  const int view = blockIdx.x;
  const float* __restrict__ w1 = view ? w1b : w1a;
  const float* __restrict__ b1 = view ? b1b : b1a;
  const float* __restrict__ w2 = view ? w2b : w2a;
  const int t = threadIdx.x;
  if (t >= 225) return;
  const int i = t / 15, j = t % 15;
  float vi = 8.0f * (float)(i - 7) * (1.0f / 7.0f);
  float vj = 8.0f * (float)(j - 7) * (1.0f / 7.0f);
  float in0 = copysignf(log2f(fabsf(vi) + 1.0f) * (1.0f / 3.0f), vi);
  float in1 = copysignf(log2f(fabsf(vj) + 1.0f) * (1.0f / 3.0f), vj);
  float acc[8] = {0.f,0.f,0.f,0.f,0.f,0.f,0.f,0.f};
  for (int u = 0; u < 512; ++u) {
    float hv = w1[2*u] * in0 + w1[2*u+1] * in1 + b1[u];
    hv = fmaxf(hv, 0.0f);
#pragma unroll
    for (int hh = 0; hh < 8; ++hh) acc[hh] += w2[hh*512 + u] * hv;
  }
#pragma unroll
  for (int hh = 0; hh < 8; ++hh)
    sg16[(view*225 + t)*8 + hh] = 16.0f / (1.0f + __expf(-acc[hh]));
}

// ---------------- fused: per-window (both views) QKV + attention + proj ------
// Identical to R4 except: OUTPUT IS FP32 (reference output dtype is float32).
__global__ __launch_bounds__(512, 2) void fused_attn(
    const float* __restrict__ x1, const float* __restrict__ x2,
    const float* __restrict__ qkvw1, const float* __restrict__ qb1, const float* __restrict__ vb1,
    const float* __restrict__ qkvw2, const float* __restrict__ qb2, const float* __restrict__ vb2,
    const float* __restrict__ pcw1, const float* __restrict__ pcb1, const float* __restrict__ ls1,
    const float* __restrict__ pcw2, const float* __restrict__ pcb2, const float* __restrict__ ls2,
    const float* __restrict__ pw1, const float* __restrict__ pb1,
    const float* __restrict__ pw2, const float* __restrict__ pb2,
    const float* __restrict__ sg16,
    float* __restrict__ outp) {
  const int win = blockIdx.x;
  const int tid = threadIdx.x;
  const int lane = tid & 63, h = tid >> 6;
  const int quad = lane >> 4, m = lane & 15;

  __shared__ __align__(16) char sm[50176];
  __shared__ float sTbl[1800];
  f16* bufX = (f16*)sm;
  f16* bufO = (f16*)(sm + 9216);
  f16* Sb   = (f16*)sm;
  f16* preB = (f16*)sm;

  const f32x4 z4 = {0.f, 0.f, 0.f, 0.f};
  f16x8 aqF[2][4], kfF[2][4], bvF[2][2][2];

  // ================= QKV GEMMs, both views =================
#pragma unroll
  for (int view = 0; view < 2; ++view) {
    const float* __restrict__ xv = (view ? x2 : x1) + (size_t)win * (NTOK * DIM);
    const float* __restrict__ W  = view ? qkvw2 : qkvw1;
    const float* __restrict__ qb = view ? qb2 : qb1;
    const float* __restrict__ vb = view ? vb2 : vb1;
    for (int sec = 0; sec < 3; ++sec) {
      f32x4 acc0[4], acc1[4];
#pragma unroll
      for (int t = 0; t < 4; ++t) { acc0[t] = z4; acc1[t] = z4; }
      for (int qtr = 0; qtr < 4; ++qtr) {
        __syncthreads();   // bufX safe to overwrite
        {
          int n = tid >> 3, col = (tid & 7) * 8;
          *(f16x8*)(bufX + n * 72 + col) = ld_f16x8(xv + n * 256 + qtr * 64 + col);
        }
        __syncthreads();   // bufX ready
        f16x8 a0[2], a1[2];
        const float* wb = W + (size_t)(sec * 256 + h * 32) * 256 + qtr * 64 + quad * 8;
#pragma unroll
        for (int ks = 0; ks < 2; ++ks) {
          a0[ks] = ld_f16x8(wb + (size_t)m * 256 + ks * 32);
          a1[ks] = ld_f16x8(wb + (size_t)(16 + m) * 256 + ks * 32);
        }
#pragma unroll
        for (int tt = 0; tt < 4; ++tt) {
#pragma unroll
          for (int ks = 0; ks < 2; ++ks) {
            f16x8 bfr = *(const f16x8*)(bufX + (tt * 16 + m) * 72 + ks * 32 + quad * 8);
            acc0[tt] = MFMA_F16(a0[ks], bfr, acc0[tt]);
            acc1[tt] = MFMA_F16(a1[ks], bfr, acc1[tt]);
          }
        }
      }
      // epilogue: bias, (l2norm q/k), write f16 [token][hd] to own head region
      float bs0[4], bs1[4];
#pragma unroll
      for (int r = 0; r < 4; ++r) {
        int c0 = h * 32 + quad * 4 + r;
        bs0[r] = (sec == 0) ? qb[c0] : (sec == 2 ? vb[c0] : 0.f);
        bs1[r] = (sec == 0) ? qb[c0 + 16] : (sec == 2 ? vb[c0 + 16] : 0.f);
      }
      f16* oh = bufO + h * 2560;
#pragma unroll
      for (int tt = 0; tt < 4; ++tt) {
        float v0[4], v1[4];
#pragma unroll
        for (int r = 0; r < 4; ++r) { v0[r] = acc0[tt][r] + bs0[r]; v1[r] = acc1[tt][r] + bs1[r]; }
        if (sec < 2) {
          float ss = 0.f;
#pragma unroll
          for (int r = 0; r < 4; ++r) ss += v0[r] * v0[r] + v1[r] * v1[r];
          ss += __shfl_xor(ss, 16, 64);
          ss += __shfl_xor(ss, 32, 64);
          float s = 1.0f / fmaxf(sqrtf(ss), 1e-12f);
#pragma unroll
          for (int r = 0; r < 4; ++r) { v0[r] *= s; v1[r] *= s; }
        }
        const int n = tt * 16 + m;
        f16x4v p0, p1;
#pragma unroll
        for (int r = 0; r < 4; ++r) { p0[r] = (f16)v0[r]; p1[r] = (f16)v1[r]; }
        *(f16x4v*)(oh + n * 40 + quad * 4)      = p0;
        *(f16x4v*)(oh + n * 40 + 16 + quad * 4) = p1;
      }
      __syncthreads();   // bufO ready
      if (sec == 0) {
#pragma unroll
        for (int rt = 0; rt < 4; ++rt)
          aqF[view][rt] = *(const f16x8*)(oh + (rt * 16 + m) * 40 + quad * 8);
      } else if (sec == 1) {
#pragma unroll
        for (int ct = 0; ct < 4; ++ct)
          kfF[view][ct] = *(const f16x8*)(oh + (ct * 16 + m) * 40 + quad * 8);
      } else {
#pragma unroll
        for (int nt = 0; nt < 2; ++nt)
#pragma unroll
          for (int kv = 0; kv < 2; ++kv) {
            f16x8 t;
#pragma unroll
            for (int j = 0; j < 8; ++j)
              t[j] = oh[(kv * 32 + quad * 8 + j) * 40 + nt * 16 + m];
            bvF[view][nt][kv] = t;
          }
      }
    }
  }
  __syncthreads();   // all fragments in regs; sm free

  // ================= attention + proj, both views =================
#pragma unroll
  for (int view = 0; view < 2; ++view) {
    const float* __restrict__ pcw = view ? pcw2 : pcw1;
    float pcwf[16];
#pragma unroll
    for (int c = 0; c < 16; ++c) pcwf[c] = pcw[h * 16 + c];
    const float pcb_h = (view ? pcb2 : pcb1)[h];
    const float lsv = (view ? ls2 : ls1)[h];
    const float scale_h = __expf(fminf(lsv, 4.6051702f));
    const float pcbs = pcb_h * scale_h;
    for (int i = tid; i < 1800; i += 512) sTbl[i] = sg16[view * 1800 + i];
    __syncthreads();   // sTbl ready; prior-view preB reads done

    f32x4 oacc[4][2];
#pragma unroll
    for (int rt = 0; rt < 4; ++rt) {
      f16x8 aq = aqF[view][rt];
      f32x4 Ss[4], Sd[4];
#pragma unroll
      for (int ct = 0; ct < 4; ++ct) {
        Ss[ct] = MFMA_F16(aq, kfF[view][ct], z4);
        Sd[ct] = MFMA_F16(aq, kfF[1 - view][ct], z4);
      }
#pragma unroll
      for (int ct = 0; ct < 4; ++ct)
#pragma unroll
        for (int r = 0; r < 4; ++r) {
          Sb[(quad * 4 + r) * 1536 + (ct * 16 + m) * 24 + h]     = (f16)Ss[ct][r];
          Sb[(quad * 4 + r) * 1536 + (ct * 16 + m) * 24 + 8 + h] = (f16)Sd[ct][r];
        }
      __syncthreads();   // B1: Sb complete (all heads' channels)

      // ---- logits: direct 16-channel mix from Sb; softmax; AV ----
      const int n = rt * 16 + m;
      const int nh_ = n >> 3, nw_ = n & 7;
      const f16* srow = Sb + m * 1536;
      float logit[16];
#pragma unroll
      for (int j = 0; j < 16; ++j) {
        int mm = (j < 8) ? (quad * 8 + j) : (32 + quad * 8 + (j - 8));
        f16x8 s0 = *(const f16x8*)(srow + mm * 24);
        f16x8 s1 = *(const f16x8*)(srow + mm * 24 + 8);
        float mix = 0.f;
#pragma unroll
        for (int c = 0; c < 8; ++c)
          mix += pcwf[c] * (float)s0[c] + pcwf[8 + c] * (float)s1[c];
        int idx = (nh_ - (mm >> 3) + 7) * 15 + (nw_ - (mm & 7) + 7);
        logit[j] = mix * scale_h + pcbs + sTbl[idx * 8 + h];
      }
      float mx = -1e30f;
#pragma unroll
      for (int j = 0; j < 16; ++j) mx = fmaxf(mx, logit[j]);
      mx = fmaxf(mx, __shfl_xor(mx, 16, 64));
      mx = fmaxf(mx, __shfl_xor(mx, 32, 64));
      float p[16], sum = 0.f;
#pragma unroll
      for (int j = 0; j < 16; ++j) { p[j] = __expf(logit[j] - mx); sum += p[j]; }
      sum += __shfl_xor(sum, 16, 64);
      sum += __shfl_xor(sum, 32, 64);
      float inv = 1.0f / sum;
      f16x8 av0, av1;
#pragma unroll
      for (int j = 0; j < 8; ++j) { av0[j] = (f16)(p[j] * inv); av1[j] = (f16)(p[8 + j] * inv); }
#pragma unroll
      for (int nt = 0; nt < 2; ++nt) {
        f32x4 z = z4;
        z = MFMA_F16(av0, bvF[view][nt][0], z);
        z = MFMA_F16(av1, bvF[view][nt][1], z);
        oacc[rt][nt] = z;
      }
      __syncthreads();   // B2: Sb reads done before next rt overwrites
    }

    // ---- pre-projection activations -> preB ----
#pragma unroll
    for (int mt = 0; mt < 4; ++mt)
#pragma unroll
      for (int nt = 0; nt < 2; ++nt)
#pragma unroll
        for (int r = 0; r < 4; ++r)
          preB[(mt * 16 + quad * 4 + r) * 264 + h * 32 + nt * 16 + m] = (f16)oacc[mt][nt][r];
    __syncthreads();   // preB ready

    // ---- proj GEMM from preB ----
    const float* __restrict__ Wp = view ? pw2 : pw1;
    const float* __restrict__ pb = view ? pb2 : pb1;
    f32x4 pacc0[4], pacc1[4];
#pragma unroll
    for (int t = 0; t < 4; ++t) { pacc0[t] = z4; pacc1[t] = z4; }
    for (int ks = 0; ks < 8; ++ks) {
      f16x8 pa0 = ld_f16x8(Wp + (size_t)(h * 32 + m) * 256 + ks * 32 + quad * 8);
      f16x8 pa1 = ld_f16x8(Wp + (size_t)(h * 32 + 16 + m) * 256 + ks * 32 + quad * 8);
#pragma unroll
      for (int tt = 0; tt < 4; ++tt) {
        f16x8 bfr = *(const f16x8*)(preB + (tt * 16 + m) * 264 + ks * 32 + quad * 8);
        pacc0[tt] = MFMA_F16(pa0, bfr, pacc0[tt]);
        pacc1[tt] = MFMA_F16(pa1, bfr, pacc1[tt]);
      }
    }
    // ---- FP32 output store (reference output dtype is float32) ----
    float* obase = outp + (size_t)(view * NWIN + win) * (NTOK * DIM);
#pragma unroll
    for (int tt = 0; tt < 4; ++tt) {
      f32x4 p0, p1;
#pragma unroll
      for (int r = 0; r < 4; ++r) {
        p0[r] = pacc0[tt][r] + pb[h * 32 + quad * 4 + r];
        p1[r] = pacc1[tt][r] + pb[h * 32 + 16 + quad * 4 + r];
      }
      const int n = tt * 16 + m;
      *(f32x4*)(obase + n * 256 + h * 32 + quad * 4)      = p0;
      *(f32x4*)(obase + n * 256 + h * 32 + 16 + quad * 4) = p1;
    }
    __syncthreads();   // preB reads done before next view reuses sm
  }
}

extern "C" void kernel_launch(void* const* d_in, const int* in_sizes, int n_in,
                              void* d_out, int out_size, void* d_ws, size_t ws_size,
                              hipStream_t stream) {
  (void)in_sizes; (void)n_in; (void)out_size; (void)ws_size;
  const float* x1   = (const float*)d_in[0];
  const float* x2   = (const float*)d_in[1];
  const float* qkvw1= (const float*)d_in[2];
  const float* qb1  = (const float*)d_in[3];
  const float* vb1  = (const float*)d_in[4];
  const float* pw1  = (const float*)d_in[5];
  const float* pb1  = (const float*)d_in[6];
  const float* ls1  = (const float*)d_in[7];
  const float* cw11 = (const float*)d_in[8];
  const float* cb11 = (const float*)d_in[9];
  const float* cw12 = (const float*)d_in[10];
  const float* pcw1 = (const float*)d_in[11];
  const float* pcb1 = (const float*)d_in[12];
  const float* qkvw2= (const float*)d_in[13];
  const float* qb2  = (const float*)d_in[14];
  const float* vb2  = (const float*)d_in[15];
  const float* pw2  = (const float*)d_in[16];
  const float* pb2  = (const float*)d_in[17];
  const float* ls2  = (const float*)d_in[18];
  const float* cw21 = (const float*)d_in[19];
  const float* cb21 = (const float*)d_in[20];
  const float* cw22 = (const float*)d_in[21];
  const float* pcw2 = (const float*)d_in[22];
  const float* pcb2 = (const float*)d_in[23];

  float* SG16 = (float*)d_ws;    // [2][225][8] f32 = 14.4 KB (only ws use)
  float* out = (float*)d_out;

  prep_cpb<<<2, 256, 0, stream>>>(cw11, cb11, cw12, cw21, cb21, cw22, SG16);
  fused_attn<<<NWIN, 512, 0, stream>>>(x1, x2,
      qkvw1, qb1, vb1, qkvw2, qb2, vb2,
      pcw1, pcb1, ls1, pcw2, pcb2, ls2,
      pw1, pb1, pw2, pb2, SG16, out);
}